// Round 2
// baseline (248.986 us; speedup 1.0000x reference)
//
#include <hip/hip_runtime.h>

// C = triu(A @ B), A,B upper-triangular fp32 4096x4096.
// R8: m97-STRUCTURE INNER LOOP. R7 was balance-fixed but per-phase-inefficient
// (430 TF device rate vs m97's 874 at same tile): reg-staging + 72KB LDS ->
// 2 blocks/CU. Now: single-buffered 32KB linear LDS + global_load_lds(16B)
// staging + XOR chunk-swizzle (swizzled per-lane GLOBAL source + swizzled
// ds_read offsets, linear LDS dest - rule both-sides-or-neither), 2 barriers
// per phase, 4 blocks/CU -> NWG=1024. Compile-time LPT re-cut: CH=12,
// splits d>=6 (atomicAdd into prep-zeroed tiles), 1233 fragments, makespan
// ~13 phases (mean 11.7).

#define N    4096
#define NB   32      // N / BM
#define BM   128
#define PK   64      // K per phase
#define NWG  1024
#define CH   12      // max phases per chunk (split-K granularity: K<=768)
#define MAXF 1280    // fragment capacity (actual: 1233)
#define MAXL 64      // max per-wg load bound for LPT buckets

typedef __attribute__((ext_vector_type(8))) __bf16 bf16x8;
typedef __attribute__((ext_vector_type(4))) float  floatx4;
typedef __attribute__((ext_vector_type(8))) unsigned short ushort8;

// ---------------- compile-time split-K schedule ----------------
struct Sched {
    unsigned short wgoff[NWG + 1];
    unsigned int   chunks[MAXF];   // bi|bj<<5|p0<<10|np<<17|atomic<<24
    int nf;
};

constexpr Sched make_sched() {
    Sched s{};
    unsigned int fr_sz[MAXF] = {};
    unsigned int fr_pk[MAXF] = {};
    int nf = 0;
    // jobs ordered d desc, bi asc; np_job = 2*(d+1) phases; split into nc chunks
    for (int d = NB - 1; d >= 0; --d) {
        const int npj  = 2 * (d + 1);
        const int nc   = (npj + CH - 1) / CH;          // nc>1 iff d>=6
        const int base = npj / nc, rem = npj % nc;
        for (int bi = 0; bi + d < NB; ++bi) {
            const int bj = bi + d;
            int p0 = 0;
            for (int c = 0; c < nc; ++c) {
                const int fnp = base + (c < rem ? 1 : 0);
                fr_sz[nf] = (unsigned)fnp;
                fr_pk[nf] = (unsigned)bi | ((unsigned)bj << 5) |
                            ((unsigned)p0 << 10) | ((unsigned)fnp << 17) |
                            ((nc > 1 ? 1u : 0u) << 24);
                ++nf;
                p0 += fnp;
            }
        }
    }
    // stable counting sort of fragments by size, descending
    int order[MAXF] = {};
    int pos = 0;
    for (int sz = CH; sz >= 1; --sz)
        for (int i = 0; i < nf; ++i)
            if ((int)fr_sz[i] == sz) order[pos++] = i;
    // LPT: assign each fragment (big first) to the min-load bin.
    int bcnt[MAXL] = {};
    int blist[MAXL][NWG] = {};
    for (int b = 0; b < NWG; ++b) blist[0][b] = NWG - 1 - b;
    bcnt[0] = NWG;
    int assign[MAXF] = {};
    int minload = 0;
    for (int k = 0; k < nf; ++k) {
        const int f = order[k];
        while (bcnt[minload] == 0) ++minload;
        const int b  = blist[minload][--bcnt[minload]];
        const int nl = minload + (int)fr_sz[f];
        blist[nl][bcnt[nl]++] = b;
        assign[f] = b;
    }
    // emit per-wg contiguous chunk lists
    int cnt[NWG] = {};
    for (int f = 0; f < nf; ++f) cnt[assign[f]]++;
    s.wgoff[0] = 0;
    for (int b = 0; b < NWG; ++b)
        s.wgoff[b + 1] = (unsigned short)(s.wgoff[b] + cnt[b]);
    int fill[NWG] = {};
    for (int f = 0; f < nf; ++f) {
        const int b = assign[f];
        s.chunks[s.wgoff[b] + fill[b]++] = fr_pk[f];
    }
    s.nf = nf;
    return s;
}

__device__ constexpr Sched g_sched = make_sched();

__device__ __forceinline__ unsigned short f32_to_bf16_rne(float f) {
    unsigned u = __builtin_bit_cast(unsigned, f);
    unsigned r = u + 0x7fffu + ((u >> 16) & 1u);
    return (unsigned short)(r >> 16);
}

__device__ __forceinline__ void gload_lds16(const unsigned short* g,
                                            unsigned short* l) {
    __builtin_amdgcn_global_load_lds(
        (const __attribute__((address_space(1))) void*)g,
        (__attribute__((address_space(3))) void*)l, 16, 0, 0);
}

// --- fused prep: A->bf16 (upper blocks), B->bf16 transposed (needed blocks),
//     zero C on strictly-lower 128-blocks AND split-K tiles (d>=6) ---
__global__ __launch_bounds__(256)
void prep_kernel(const float* __restrict__ A, const float* __restrict__ B,
                 unsigned short* __restrict__ Ab, unsigned short* __restrict__ Bt,
                 float* __restrict__ C) {
    __shared__ float tile[64][65];
    const int bx = blockIdx.x, by = blockIdx.y;      // 64-granule col/row
    const int x0 = bx * 64, y0 = by * 64;
    const int xb = bx >> 1, yb = by >> 1;            // 128-blocks
    const int t  = threadIdx.x;
    const int tr = t >> 2, tc = (t & 3) * 16;        // 64x(16/thread)

    // A: rows y0.., k-cols x0..; needed iff k-block >= row-block
    if (xb >= yb) {
        const float* src = A + (size_t)(y0 + tr) * N + x0 + tc;
        const float4 v0 = ((const float4*)src)[0];
        const float4 v1 = ((const float4*)src)[1];
        const float4 v2 = ((const float4*)src)[2];
        const float4 v3 = ((const float4*)src)[3];
        ushort8 o0, o1;
        o0[0]=f32_to_bf16_rne(v0.x); o0[1]=f32_to_bf16_rne(v0.y);
        o0[2]=f32_to_bf16_rne(v0.z); o0[3]=f32_to_bf16_rne(v0.w);
        o0[4]=f32_to_bf16_rne(v1.x); o0[5]=f32_to_bf16_rne(v1.y);
        o0[6]=f32_to_bf16_rne(v1.z); o0[7]=f32_to_bf16_rne(v1.w);
        o1[0]=f32_to_bf16_rne(v2.x); o1[1]=f32_to_bf16_rne(v2.y);
        o1[2]=f32_to_bf16_rne(v2.z); o1[3]=f32_to_bf16_rne(v2.w);
        o1[4]=f32_to_bf16_rne(v3.x); o1[5]=f32_to_bf16_rne(v3.y);
        o1[6]=f32_to_bf16_rne(v3.z); o1[7]=f32_to_bf16_rne(v3.w);
        unsigned short* dst = Ab + (size_t)(y0 + tr) * N + x0 + tc;
        ((ushort8*)dst)[0] = o0;
        ((ushort8*)dst)[1] = o1;
    }
    // Bt[j][k]=B[k][j]: j rows y0.., k cols x0..; needed iff k-block <= j-block
    if (xb <= yb) {
        const float* src = B + (size_t)(x0 + tr) * N + y0 + tc;   // B[k][j]
        const float4 v0 = ((const float4*)src)[0];
        const float4 v1 = ((const float4*)src)[1];
        const float4 v2 = ((const float4*)src)[2];
        const float4 v3 = ((const float4*)src)[3];
        float* d = &tile[tr][tc];
        d[0]=v0.x; d[1]=v0.y; d[2]=v0.z; d[3]=v0.w;
        d[4]=v1.x; d[5]=v1.y; d[6]=v1.z; d[7]=v1.w;
        d[8]=v2.x; d[9]=v2.y; d[10]=v2.z; d[11]=v2.w;
        d[12]=v3.x; d[13]=v3.y; d[14]=v3.z; d[15]=v3.w;
        __syncthreads();
        ushort8 o0, o1;
        #pragma unroll
        for (int i = 0; i < 8; ++i) o0[i] = f32_to_bf16_rne(tile[tc + i][tr]);
        #pragma unroll
        for (int i = 0; i < 8; ++i) o1[i] = f32_to_bf16_rne(tile[tc + 8 + i][tr]);
        unsigned short* dst = Bt + (size_t)(y0 + tr) * N + x0 + tc;
        ((ushort8*)dst)[0] = o0;
        ((ushort8*)dst)[1] = o1;
    }
    // C zeros: strictly-lower 128-blocks + split-K (atomicAdd) tiles d>=6
    if (xb < yb || (xb - yb) >= 6) {
        float4 z = {0.f, 0.f, 0.f, 0.f};
        float* dst = C + (size_t)(y0 + tr) * N + x0 + tc;
        ((float4*)dst)[0] = z; ((float4*)dst)[1] = z;
        ((float4*)dst)[2] = z; ((float4*)dst)[3] = z;
    }
}

// --- balanced split-K triangular MFMA GEMM, m97-style global_load_lds loop ---
__global__ __launch_bounds__(256, 4)
void trimm_kernel(const unsigned short* __restrict__ Ab,
                  const unsigned short* __restrict__ Bt,
                  float* __restrict__ C) {
    __shared__ unsigned short sA[BM * PK];   // 16 KiB, linear [128][64]
    __shared__ unsigned short sB[BM * PK];   // 16 KiB

    const int tid  = threadIdx.x;
    const int w    = tid >> 6;
    const int lane = tid & 63;
    const int quad = lane >> 4;
    const int l15  = lane & 15;

    const int m0 = (w >> 1) * 64;
    const int n0 = (w & 1) * 64;

    // staging map: instr i covers rows w*32+i*8 .. +8; lane l -> row +(l>>3),
    // 16B chunk l&7. Global source chunk XOR-swizzled: (l&7) ^ (l>>3)
    // (row&7 == l>>3 since base rows are multiples of 8).
    const int srow   = lane >> 3;
    const int schunk = ((lane & 7) ^ srow) * 8;   // ushort offset in row
    int rr[4];
    unsigned short* dA[4];
    unsigned short* dB[4];
    #pragma unroll
    for (int i = 0; i < 4; ++i) {
        rr[i] = w * 32 + i * 8 + srow;
        dA[i] = sA + (w * 32 + i * 8) * PK;   // wave-uniform base
        dB[i] = sB + (w * 32 + i * 8) * PK;
    }

    // read-side swizzle: row&7 == l15&7; chunk(h) = (h*4+quad) ^ (l15&7)
    const int e  = l15 & 7;
    const int c0 = ((quad ^ (e & 3)) + 4 * (e >> 2)) * 8;        // h=0
    const int c1 = ((quad ^ (e & 3)) + 4 * (1 ^ (e >> 2))) * 8;  // h=1

    const int b  = (int)blockIdx.x;
    const int j0 = g_sched.wgoff[b];
    const int j1 = g_sched.wgoff[b + 1];

    for (int j = j0; j < j1; ++j) {
        const unsigned int ck = g_sched.chunks[j];
        const int bi   = ck & 31;
        const int bj   = (ck >> 5) & 31;
        const int p0   = (ck >> 10) & 127;
        const int cnp  = (ck >> 17) & 127;     // phases in this chunk
        const bool is_at = (ck >> 24) & 1u;

        const int row0 = bi * BM;
        const int col0 = bj * BM;
        const int k0   = bi * BM + p0 * PK;    // chunk K start

        floatx4 acc[4][4] = {};

        const unsigned short* gA[4];
        const unsigned short* gB[4];
        #pragma unroll
        for (int i = 0; i < 4; ++i) {
            gA[i] = Ab + (size_t)(row0 + rr[i]) * N + k0 + schunk;
            gB[i] = Bt + (size_t)(col0 + rr[i]) * N + k0 + schunk;
        }

        for (int ph = 0; ph < cnp; ++ph) {
            #pragma unroll
            for (int i = 0; i < 4; ++i) { gload_lds16(gA[i], dA[i]); gA[i] += PK; }
            #pragma unroll
            for (int i = 0; i < 4; ++i) { gload_lds16(gB[i], dB[i]); gB[i] += PK; }
            __syncthreads();               // drains vmcnt(0) + barrier
            #pragma unroll
            for (int h = 0; h < 2; ++h) {
                const int ch = h ? c1 : c0;
                bf16x8 af[4], bfr[4];
                #pragma unroll
                for (int t = 0; t < 4; ++t) {
                    af[t]  = *(const bf16x8*)&sA[(m0 + t * 16 + l15) * PK + ch];
                    bfr[t] = *(const bf16x8*)&sB[(n0 + t * 16 + l15) * PK + ch];
                }
                #pragma unroll
                for (int tm = 0; tm < 4; ++tm)
                    #pragma unroll
                    for (int tn = 0; tn < 4; ++tn)
                        acc[tm][tn] = __builtin_amdgcn_mfma_f32_16x16x32_bf16(
                            af[tm], bfr[tn], acc[tm][tn], 0, 0, 0);
            }
            __syncthreads();               // protect LDS before next overwrite
        }

        // epilogue. C/D layout: col=l15, row=quad*4+r
        #pragma unroll
        for (int tm = 0; tm < 4; ++tm) {
            const int grow_base = row0 + m0 + tm * 16 + quad * 4;
            #pragma unroll
            for (int tn = 0; tn < 4; ++tn) {
                const int gcol = col0 + n0 + tn * 16 + l15;
                #pragma unroll
                for (int r = 0; r < 4; ++r) {
                    const int grow = grow_base + r;
                    const float v = acc[tm][tn][r];
                    if (is_at) {
                        atomicAdd(&C[(size_t)grow * N + gcol], v);   // split tile
                    } else if (bi != bj) {
                        C[(size_t)grow * N + gcol] = v;              // single writer
                    } else {
                        C[(size_t)grow * N + gcol] = (gcol >= grow) ? v : 0.0f;
                    }
                }
            }
        }
    }
}

extern "C" void kernel_launch(void* const* d_in, const int* in_sizes, int n_in,
                              void* d_out, int out_size, void* d_ws, size_t ws_size,
                              hipStream_t stream) {
    const float* A = (const float*)d_in[0];
    const float* B = (const float*)d_in[1];
    float* C = (float*)d_out;

    unsigned short* Ab = (unsigned short*)d_ws;              // 32 MiB
    unsigned short* Bt = Ab + (size_t)N * N;                 // 32 MiB

    prep_kernel<<<dim3(N / 64, N / 64), dim3(256), 0, stream>>>(A, B, Ab, Bt, C);
    trimm_kernel<<<dim3(NWG), dim3(256), 0, stream>>>(Ab, Bt, C);
}

// Round 3
// 218.967 us; speedup vs baseline: 1.1371x; 1.1371x over previous
//
#include <hip/hip_runtime.h>

// C = triu(A @ B), A,B upper-triangular fp32 4096x4096.
// R9: gload_lds + DOUBLE-BUFFER 2-PHASE PIPELINE. R8 proved the swizzle
// (bank conflicts 0) but its single-buffered loop had zero intra-wg overlap
// (stage -> vmcnt(0) -> compute serially): 270 TF. R7 proved prefetch-before-
// compute (388 TF) but paid reg-staging + 72KB LDS. Now: T3 minimum-2-phase --
// stage phase p+1 into buf^1 via global_load_lds(16B) BEFORE computing buf,
// one __syncthreads per phase (its vmcnt(0) drain lands after compute has
// hidden the latency). LDS 64KB -> 2 blocks/CU, NWG=512 all-resident,
// R7 schedule (CH=24, d>=12 split, makespan ~26). Swizzled global source +
// swizzled ds_read offsets, linear LDS dest (verified R8).

#define N    4096
#define NB   32      // N / BM
#define BM   128
#define PK   64      // K per phase
#define NWG  512
#define CH   24      // max phases per chunk (split-K granularity: K<=1536)
#define MAXF 832     // fragment capacity (actual: 774)
#define MAXL 64      // max per-wg load bound for LPT buckets

typedef __attribute__((ext_vector_type(8))) __bf16 bf16x8;
typedef __attribute__((ext_vector_type(4))) float  floatx4;
typedef __attribute__((ext_vector_type(8))) unsigned short ushort8;

// ---------------- compile-time split-K schedule ----------------
struct Sched {
    unsigned short wgoff[NWG + 1];
    unsigned int   chunks[MAXF];   // bi|bj<<5|p0<<10|np<<17|atomic<<24
    int nf;
};

constexpr Sched make_sched() {
    Sched s{};
    unsigned int fr_sz[MAXF] = {};
    unsigned int fr_pk[MAXF] = {};
    int nf = 0;
    // jobs ordered d desc, bi asc; np_job = 2*(d+1) phases; split into nc chunks
    for (int d = NB - 1; d >= 0; --d) {
        const int npj  = 2 * (d + 1);
        const int nc   = (npj + CH - 1) / CH;          // nc>1 iff d>=12
        const int base = npj / nc, rem = npj % nc;
        for (int bi = 0; bi + d < NB; ++bi) {
            const int bj = bi + d;
            int p0 = 0;
            for (int c = 0; c < nc; ++c) {
                const int fnp = base + (c < rem ? 1 : 0);
                fr_sz[nf] = (unsigned)fnp;
                fr_pk[nf] = (unsigned)bi | ((unsigned)bj << 5) |
                            ((unsigned)p0 << 10) | ((unsigned)fnp << 17) |
                            ((nc > 1 ? 1u : 0u) << 24);
                ++nf;
                p0 += fnp;
            }
        }
    }
    // stable counting sort of fragments by size, descending
    int order[MAXF] = {};
    int pos = 0;
    for (int sz = CH; sz >= 1; --sz)
        for (int i = 0; i < nf; ++i)
            if ((int)fr_sz[i] == sz) order[pos++] = i;
    // LPT: assign each fragment (big first) to the min-load bin.
    int bcnt[MAXL] = {};
    int blist[MAXL][NWG] = {};
    for (int b = 0; b < NWG; ++b) blist[0][b] = NWG - 1 - b;
    bcnt[0] = NWG;
    int assign[MAXF] = {};
    int minload = 0;
    for (int k = 0; k < nf; ++k) {
        const int f = order[k];
        while (bcnt[minload] == 0) ++minload;
        const int b  = blist[minload][--bcnt[minload]];
        const int nl = minload + (int)fr_sz[f];
        blist[nl][bcnt[nl]++] = b;
        assign[f] = b;
    }
    // emit per-wg contiguous chunk lists
    int cnt[NWG] = {};
    for (int f = 0; f < nf; ++f) cnt[assign[f]]++;
    s.wgoff[0] = 0;
    for (int b = 0; b < NWG; ++b)
        s.wgoff[b + 1] = (unsigned short)(s.wgoff[b] + cnt[b]);
    int fill[NWG] = {};
    for (int f = 0; f < nf; ++f) {
        const int b = assign[f];
        s.chunks[s.wgoff[b] + fill[b]++] = fr_pk[f];
    }
    s.nf = nf;
    return s;
}

__device__ constexpr Sched g_sched = make_sched();

__device__ __forceinline__ unsigned short f32_to_bf16_rne(float f) {
    unsigned u = __builtin_bit_cast(unsigned, f);
    unsigned r = u + 0x7fffu + ((u >> 16) & 1u);
    return (unsigned short)(r >> 16);
}

__device__ __forceinline__ void gload_lds16(const unsigned short* g,
                                            unsigned short* l) {
    __builtin_amdgcn_global_load_lds(
        (const __attribute__((address_space(1))) void*)g,
        (__attribute__((address_space(3))) void*)l, 16, 0, 0);
}

// --- fused prep: A->bf16 (upper blocks), B->bf16 transposed (needed blocks),
//     zero C on strictly-lower 128-blocks AND split-K tiles (d>=12) ---
__global__ __launch_bounds__(256)
void prep_kernel(const float* __restrict__ A, const float* __restrict__ B,
                 unsigned short* __restrict__ Ab, unsigned short* __restrict__ Bt,
                 float* __restrict__ C) {
    __shared__ float tile[64][65];
    const int bx = blockIdx.x, by = blockIdx.y;      // 64-granule col/row
    const int x0 = bx * 64, y0 = by * 64;
    const int xb = bx >> 1, yb = by >> 1;            // 128-blocks
    const int t  = threadIdx.x;
    const int tr = t >> 2, tc = (t & 3) * 16;        // 64x(16/thread)

    // A: rows y0.., k-cols x0..; needed iff k-block >= row-block
    if (xb >= yb) {
        const float* src = A + (size_t)(y0 + tr) * N + x0 + tc;
        const float4 v0 = ((const float4*)src)[0];
        const float4 v1 = ((const float4*)src)[1];
        const float4 v2 = ((const float4*)src)[2];
        const float4 v3 = ((const float4*)src)[3];
        ushort8 o0, o1;
        o0[0]=f32_to_bf16_rne(v0.x); o0[1]=f32_to_bf16_rne(v0.y);
        o0[2]=f32_to_bf16_rne(v0.z); o0[3]=f32_to_bf16_rne(v0.w);
        o0[4]=f32_to_bf16_rne(v1.x); o0[5]=f32_to_bf16_rne(v1.y);
        o0[6]=f32_to_bf16_rne(v1.z); o0[7]=f32_to_bf16_rne(v1.w);
        o1[0]=f32_to_bf16_rne(v2.x); o1[1]=f32_to_bf16_rne(v2.y);
        o1[2]=f32_to_bf16_rne(v2.z); o1[3]=f32_to_bf16_rne(v2.w);
        o1[4]=f32_to_bf16_rne(v3.x); o1[5]=f32_to_bf16_rne(v3.y);
        o1[6]=f32_to_bf16_rne(v3.z); o1[7]=f32_to_bf16_rne(v3.w);
        unsigned short* dst = Ab + (size_t)(y0 + tr) * N + x0 + tc;
        ((ushort8*)dst)[0] = o0;
        ((ushort8*)dst)[1] = o1;
    }
    // Bt[j][k]=B[k][j]: j rows y0.., k cols x0..; needed iff k-block <= j-block
    if (xb <= yb) {
        const float* src = B + (size_t)(x0 + tr) * N + y0 + tc;   // B[k][j]
        const float4 v0 = ((const float4*)src)[0];
        const float4 v1 = ((const float4*)src)[1];
        const float4 v2 = ((const float4*)src)[2];
        const float4 v3 = ((const float4*)src)[3];
        float* d = &tile[tr][tc];
        d[0]=v0.x; d[1]=v0.y; d[2]=v0.z; d[3]=v0.w;
        d[4]=v1.x; d[5]=v1.y; d[6]=v1.z; d[7]=v1.w;
        d[8]=v2.x; d[9]=v2.y; d[10]=v2.z; d[11]=v2.w;
        d[12]=v3.x; d[13]=v3.y; d[14]=v3.z; d[15]=v3.w;
        __syncthreads();
        ushort8 o0, o1;
        #pragma unroll
        for (int i = 0; i < 8; ++i) o0[i] = f32_to_bf16_rne(tile[tc + i][tr]);
        #pragma unroll
        for (int i = 0; i < 8; ++i) o1[i] = f32_to_bf16_rne(tile[tc + 8 + i][tr]);
        unsigned short* dst = Bt + (size_t)(y0 + tr) * N + x0 + tc;
        ((ushort8*)dst)[0] = o0;
        ((ushort8*)dst)[1] = o1;
    }
    // C zeros: strictly-lower 128-blocks + split-K (atomicAdd) tiles d>=12
    if (xb < yb || (xb - yb) >= 12) {
        float4 z = {0.f, 0.f, 0.f, 0.f};
        float* dst = C + (size_t)(y0 + tr) * N + x0 + tc;
        ((float4*)dst)[0] = z; ((float4*)dst)[1] = z;
        ((float4*)dst)[2] = z; ((float4*)dst)[3] = z;
    }
}

// --- balanced split-K triangular MFMA GEMM, dbuf global_load_lds pipeline ---
__global__ __launch_bounds__(256, 2)
void trimm_kernel(const unsigned short* __restrict__ Ab,
                  const unsigned short* __restrict__ Bt,
                  float* __restrict__ C) {
    __shared__ unsigned short sA[2][BM * PK];   // 2 x 16 KiB, linear [128][64]
    __shared__ unsigned short sB[2][BM * PK];   // 2 x 16 KiB

    const int tid  = threadIdx.x;
    const int w    = tid >> 6;
    const int lane = tid & 63;
    const int quad = lane >> 4;
    const int l15  = lane & 15;

    const int m0 = (w >> 1) * 64;
    const int n0 = (w & 1) * 64;

    // staging map: instr i covers rows w*32+i*8 .. +8; lane l -> row +(l>>3),
    // 16B chunk l&7. Global source chunk XOR-swizzled: (l&7) ^ (l>>3)
    // => LDS[r][c] = G[r][c ^ (r&7)] with linear LDS dest. (verified R8)
    const int srow   = lane >> 3;
    const int schunk = ((lane & 7) ^ srow) * 8;   // ushort offset in row
    int rr[4], ldso[4];
    #pragma unroll
    for (int i = 0; i < 4; ++i) {
        rr[i]   = w * 32 + i * 8 + srow;
        ldso[i] = (w * 32 + i * 8) * PK;          // wave-uniform LDS base
    }

    // read-side swizzle: row&7 == l15&7 = e; chunk(h) = (h*4+quad) ^ e
    const int e  = l15 & 7;
    const int c0 = ((quad ^ (e & 3)) + 4 * (e >> 2)) * 8;        // h=0
    const int c1 = ((quad ^ (e & 3)) + 4 * (1 ^ (e >> 2))) * 8;  // h=1

    const int b  = (int)blockIdx.x;
    const int j0 = g_sched.wgoff[b];
    const int j1 = g_sched.wgoff[b + 1];

    int cur = 0;   // buffer holding the phase about to be computed

    for (int j = j0; j < j1; ++j) {
        const unsigned int ck = g_sched.chunks[j];
        const int bi   = ck & 31;
        const int bj   = (ck >> 5) & 31;
        const int p0   = (ck >> 10) & 127;
        const int cnp  = (ck >> 17) & 127;     // phases in this chunk (>=2)
        const bool is_at = (ck >> 24) & 1u;

        const int row0 = bi * BM;
        const int col0 = bj * BM;
        const int k0   = bi * BM + p0 * PK;    // chunk K start

        floatx4 acc[4][4] = {};

        const unsigned short* gA[4];
        const unsigned short* gB[4];
        #pragma unroll
        for (int i = 0; i < 4; ++i) {
            gA[i] = Ab + (size_t)(row0 + rr[i]) * N + k0 + schunk;
            gB[i] = Bt + (size_t)(col0 + rr[i]) * N + k0 + schunk;
        }

        // prologue: stage phase 0 into cur^1 (safe: lagging waves of the
        // previous chunk are tail-computing from cur)
        cur ^= 1;
        #pragma unroll
        for (int i = 0; i < 4; ++i) { gload_lds16(gA[i], &sA[cur][ldso[i]]); gA[i] += PK; }
        #pragma unroll
        for (int i = 0; i < 4; ++i) { gload_lds16(gB[i], &sB[cur][ldso[i]]); gB[i] += PK; }
        __syncthreads();   // vmcnt(0) drain + sync

        for (int ph = 0; ph < cnp - 1; ++ph) {
            // stage next phase into the other buffer (in flight across compute)
            const int nxt = cur ^ 1;
            #pragma unroll
            for (int i = 0; i < 4; ++i) { gload_lds16(gA[i], &sA[nxt][ldso[i]]); gA[i] += PK; }
            #pragma unroll
            for (int i = 0; i < 4; ++i) { gload_lds16(gB[i], &sB[nxt][ldso[i]]); gB[i] += PK; }
            // compute current buffer
            #pragma unroll
            for (int h = 0; h < 2; ++h) {
                const int ch = h ? c1 : c0;
                bf16x8 af[4], bfr[4];
                #pragma unroll
                for (int t = 0; t < 4; ++t) {
                    af[t]  = *(const bf16x8*)&sA[cur][(m0 + t * 16 + l15) * PK + ch];
                    bfr[t] = *(const bf16x8*)&sB[cur][(n0 + t * 16 + l15) * PK + ch];
                }
                #pragma unroll
                for (int tm = 0; tm < 4; ++tm)
                    #pragma unroll
                    for (int tn = 0; tn < 4; ++tn)
                        acc[tm][tn] = __builtin_amdgcn_mfma_f32_16x16x32_bf16(
                            af[tm], bfr[tn], acc[tm][tn], 0, 0, 0);
            }
            __syncthreads();   // next buffer staged + all done reading cur
            cur = nxt;
        }
        {   // tail phase: compute cur, no stage, no barrier
            #pragma unroll
            for (int h = 0; h < 2; ++h) {
                const int ch = h ? c1 : c0;
                bf16x8 af[4], bfr[4];
                #pragma unroll
                for (int t = 0; t < 4; ++t) {
                    af[t]  = *(const bf16x8*)&sA[cur][(m0 + t * 16 + l15) * PK + ch];
                    bfr[t] = *(const bf16x8*)&sB[cur][(n0 + t * 16 + l15) * PK + ch];
                }
                #pragma unroll
                for (int tm = 0; tm < 4; ++tm)
                    #pragma unroll
                    for (int tn = 0; tn < 4; ++tn)
                        acc[tm][tn] = __builtin_amdgcn_mfma_f32_16x16x32_bf16(
                            af[tm], bfr[tn], acc[tm][tn], 0, 0, 0);
            }
        }

        // epilogue. C/D layout: col=l15, row=quad*4+r
        #pragma unroll
        for (int tm = 0; tm < 4; ++tm) {
            const int grow_base = row0 + m0 + tm * 16 + quad * 4;
            #pragma unroll
            for (int tn = 0; tn < 4; ++tn) {
                const int gcol = col0 + n0 + tn * 16 + l15;
                #pragma unroll
                for (int r = 0; r < 4; ++r) {
                    const int grow = grow_base + r;
                    const float v = acc[tm][tn][r];
                    if (is_at) {
                        atomicAdd(&C[(size_t)grow * N + gcol], v);   // split tile
                    } else if (bi != bj) {
                        C[(size_t)grow * N + gcol] = v;              // single writer
                    } else {
                        C[(size_t)grow * N + gcol] = (gcol >= grow) ? v : 0.0f;
                    }
                }
            }
        }
    }
}

extern "C" void kernel_launch(void* const* d_in, const int* in_sizes, int n_in,
                              void* d_out, int out_size, void* d_ws, size_t ws_size,
                              hipStream_t stream) {
    const float* A = (const float*)d_in[0];
    const float* B = (const float*)d_in[1];
    float* C = (float*)d_out;

    unsigned short* Ab = (unsigned short*)d_ws;              // 32 MiB
    unsigned short* Bt = Ab + (size_t)N * N;                 // 32 MiB

    prep_kernel<<<dim3(N / 64, N / 64), dim3(256), 0, stream>>>(A, B, Ab, Bt, C);
    trimm_kernel<<<dim3(NWG), dim3(256), 0, stream>>>(Ab, Bt, C);
}